// Round 3
// baseline (2407.617 us; speedup 1.0000x reference)
//
#include <hip/hip_runtime.h>
#include <type_traits>
#include <utility>

// Problem constants: T=2048, B=256, F=64, H=256, O=1
#define T_STEPS 2048
#define BATCH   256
#define FEAT    64
#define HID     256
#define KAUG    320   // FEAT + HID
#define NW      8     // waves per block
#define KCH     40    // KAUG / NW  (k-chunk per wave)

// Compile-time unroll: indices are integral_constants, so every wreg[...] GEP
// is constant at SROA time -> alloca scalarized -> true register residency.
// (Rounds 1-2: runtime-indexed loads defeated SROA; array went to scratch ->
//  64MB WRITE_SIZE spill traffic, VALUBusy 31-37%.)
template <int N>
struct Unroll {
    template <typename F>
    __device__ __forceinline__ static void run(F&& f) {
        Unroll<N - 1>::run(f);
        f(std::integral_constant<int, N - 1>{});
    }
};
template <>
struct Unroll<0> {
    template <typename F>
    __device__ __forceinline__ static void run(F&&) {}
};

// fast tanh: tanh(z) = 1 - 2/(exp(2z)+1). Saturates correctly at +/-inf.
__device__ __forceinline__ float fast_tanh(float z) {
    float e = __expf(2.0f * z);
    return 1.0f - 2.0f * __builtin_amdgcn_rcpf(e + 1.0f);
}

// One block per batch element, 512 threads = 8 waves = 2 waves/SIMD.
// Wave w owns k-range [40w, 40w+40) of a=[x_t; h]; lane l owns neurons 4l..4l+3.
// Weights register-resident: 160 VGPRs/lane (fits 256-VGPR cap at waves-per-eu=2).
__global__ void __launch_bounds__(512, 2)
rnn_kernel(const float* __restrict__ x,    // (T, B, F)
           const float* __restrict__ W0,   // (H, F+H) row-major
           const float* __restrict__ b0,   // (H)
           const float* __restrict__ Wfc,  // (1, H)
           const float* __restrict__ bfc,  // (1)
           float* __restrict__ out)        // (B, T), pre-zeroed
{
    const int b    = blockIdx.x;
    const int tid  = threadIdx.x;
    const int w    = tid >> 6;
    const int lane = tid & 63;
    const int kbase = KCH * w;

    __shared__ float a_buf[2][KAUG];   // double-buffered augmented input
    __shared__ float part[NW][HID];    // per-wave partial sums

    // wreg[kk][n] = W0[4*lane+n][kbase+kk]  -- all indices compile-time constant
    float wreg[KCH][4];
    {
        const float* w0p = W0 + 4 * lane * KAUG + kbase;
        Unroll<KCH>::run([&](auto kk) {
            Unroll<4>::run([&](auto n) {
                wreg[kk.value][n.value] = w0p[n.value * KAUG + kk.value];
            });
        });
    }

    float b0_r = 0.0f, wfc_r = 0.0f;
    if (tid < HID) { b0_r = b0[tid]; wfc_r = Wfc[tid]; }
    const float bfc_r = bfc[0];

    // prologue: a_buf[0] = [x_0 ; h0=0]
    if (tid < FEAT) a_buf[0][tid] = x[b * FEAT + tid];
    if (tid < HID)  a_buf[0][FEAT + tid] = 0.0f;
    __syncthreads();

    for (int t = 0; t < T_STEPS; ++t) {
        const int cur = t & 1;
        const int nxt = cur ^ 1;

        // prefetch x for step t+1 (hidden under FMA phase)
        float xnext = 0.0f;
        if (tid < FEAT) {
            int tn = (t + 1 < T_STEPS) ? (t + 1) : t;
            xnext = x[tn * (BATCH * FEAT) + b * FEAT + tid];
        }

        // ---- FMA phase: 160 fp32 FMAs/lane, 4 independent acc chains,
        // fed by 10 uniform-address ds_read_b128 broadcasts (conflict-free)
        float acc[4] = {0.f, 0.f, 0.f, 0.f};
        const float4* a4 = reinterpret_cast<const float4*>(&a_buf[cur][kbase]);
        Unroll<KCH / 4>::run([&](auto c) {
            const float4 av = a4[c.value];
            Unroll<4>::run([&](auto n) {
                acc[n.value] = fmaf(wreg[4 * c.value + 0][n.value], av.x, acc[n.value]);
                acc[n.value] = fmaf(wreg[4 * c.value + 1][n.value], av.y, acc[n.value]);
                acc[n.value] = fmaf(wreg[4 * c.value + 2][n.value], av.z, acc[n.value]);
                acc[n.value] = fmaf(wreg[4 * c.value + 3][n.value], av.w, acc[n.value]);
            });
        });

        // partials: contiguous b128 store, conflict-free
        *reinterpret_cast<float4*>(&part[w][4 * lane]) =
            make_float4(acc[0], acc[1], acc[2], acc[3]);
        __syncthreads();

        // ---- reduce phase: waves 0-3 active, thread tid owns neuron tid
        if (tid < HID) {
            float s = b0_r;
            Unroll<NW>::run([&](auto ww) { s += part[ww.value][tid]; });
            float h = fast_tanh(s);
            a_buf[nxt][FEAT + tid] = h;
            if (tid < FEAT) a_buf[nxt][tid] = xnext;

            // out[b][t] = Wfc . h + bfc
            float p = wfc_r * h;
#pragma unroll
            for (int m = 32; m >= 1; m >>= 1) p += __shfl_xor(p, m, 64);
            if (lane == 0) {
                atomicAdd(&out[b * T_STEPS + t], p + (w == 0 ? bfc_r : 0.0f));
            }
        }
        __syncthreads();   // a_buf[nxt] complete before next step's FMA phase
    }
}

extern "C" void kernel_launch(void* const* d_in, const int* in_sizes, int n_in,
                              void* d_out, int out_size, void* d_ws, size_t ws_size,
                              hipStream_t stream) {
    const float* x   = (const float*)d_in[0];
    const float* W0  = (const float*)d_in[1];
    const float* b0  = (const float*)d_in[2];
    const float* Wfc = (const float*)d_in[3];
    const float* bfc = (const float*)d_in[4];
    // d_in[5] = feature_n == 0 -> no autoregressive tail
    float* out = (float*)d_out;

    hipMemsetAsync(out, 0, (size_t)out_size * sizeof(float), stream);
    rnn_kernel<<<dim3(BATCH), dim3(512), 0, stream>>>(x, W0, b0, Wfc, bfc, out);
}

// Round 4
// 2232.651 us; speedup vs baseline: 1.0784x; 1.0784x over previous
//
#include <hip/hip_runtime.h>
#include <type_traits>
#include <utility>

// Problem constants: T=2048, B=256, F=64, H=256, O=1
#define T_STEPS 2048
#define BATCH   256
#define FEAT    64
#define HID     256
#define KAUG    320   // FEAT + HID
#define NTHR    1024  // threads per block
#define NW      16    // waves per block (4 waves/EU -> VGPR cap 128, unambiguous)
#define KCH     20    // KAUG / NW  (k-chunk per wave) -> 80 weight VGPRs/lane

// Rounds 2-3: 160 weights/lane at __launch_bounds__(512,2) exceeded the real
// VGPR budget (~128, not 256) -> RA spilled the longest-live-range values (the
// weights) to scratch: WRITE_SIZE=64MiB, VALUBusy 37%, VGPR_Count=100.
// Fix: 16 waves, 80 weights/lane => ~110 live < 128 cap with margin.

template <int N>
struct Unroll {
    template <typename F>
    __device__ __forceinline__ static void run(F&& f) {
        Unroll<N - 1>::run(f);
        f(std::integral_constant<int, N - 1>{});
    }
};
template <>
struct Unroll<0> {
    template <typename F>
    __device__ __forceinline__ static void run(F&&) {}
};

// fast tanh: tanh(z) = 1 - 2/(exp(2z)+1). Saturates correctly at +/-inf.
__device__ __forceinline__ float fast_tanh(float z) {
    float e = __expf(2.0f * z);
    return 1.0f - 2.0f * __builtin_amdgcn_rcpf(e + 1.0f);
}

// One block per batch element, 1024 threads = 16 waves = 4 waves/SIMD.
// Wave w owns k-range [20w, 20w+20) of a=[x_t; h]; lane l owns neurons 4l..4l+3.
__global__ void __launch_bounds__(NTHR)
rnn_kernel(const float* __restrict__ x,    // (T, B, F)
           const float* __restrict__ W0,   // (H, F+H) row-major
           const float* __restrict__ b0,   // (H)
           const float* __restrict__ Wfc,  // (1, H)
           const float* __restrict__ bfc,  // (1)
           float* __restrict__ out)        // (B, T), pre-zeroed
{
    const int b    = blockIdx.x;
    const int tid  = threadIdx.x;
    const int w    = tid >> 6;
    const int lane = tid & 63;
    const int kbase = KCH * w;

    __shared__ float a_buf[2][KAUG];   // double-buffered augmented input
    __shared__ float part[NW][HID];    // per-wave partial sums (16 KB)

    // wreg[kk][n] = W0[4*lane+n][kbase+kk]  (80 VGPRs/lane)
    float wreg[KCH][4];
    {
        const float* w0p = W0 + 4 * lane * KAUG + kbase;
        Unroll<KCH>::run([&](auto kk) {
            Unroll<4>::run([&](auto n) {
                wreg[kk.value][n.value] = w0p[n.value * KAUG + kk.value];
            });
        });
    }

    float b0_r = 0.0f, wfc_r = 0.0f;
    if (tid < HID) { b0_r = b0[tid]; wfc_r = Wfc[tid]; }
    const float bfc_r = bfc[0];

    // prologue: a_buf[0] = [x_0 ; h0=0]
    if (tid < FEAT) a_buf[0][tid] = x[b * FEAT + tid];
    if (tid < HID)  a_buf[0][FEAT + tid] = 0.0f;
    __syncthreads();

    for (int t = 0; t < T_STEPS; ++t) {
        const int cur = t & 1;
        const int nxt = cur ^ 1;

        // prefetch x for step t+1 (hidden under FMA phase)
        float xnext = 0.0f;
        if (tid < FEAT) {
            int tn = (t + 1 < T_STEPS) ? (t + 1) : t;
            xnext = x[tn * (BATCH * FEAT) + b * FEAT + tid];
        }

        // ---- FMA phase: 80 fp32 FMAs/lane, 4 independent acc chains,
        // fed by 5 uniform-address ds_read_b128 broadcasts (conflict-free)
        float acc[4] = {0.f, 0.f, 0.f, 0.f};
        const float4* a4 = reinterpret_cast<const float4*>(&a_buf[cur][kbase]);
        Unroll<KCH / 4>::run([&](auto c) {
            const float4 av = a4[c.value];
            Unroll<4>::run([&](auto n) {
                acc[n.value] = fmaf(wreg[4 * c.value + 0][n.value], av.x, acc[n.value]);
                acc[n.value] = fmaf(wreg[4 * c.value + 1][n.value], av.y, acc[n.value]);
                acc[n.value] = fmaf(wreg[4 * c.value + 2][n.value], av.z, acc[n.value]);
                acc[n.value] = fmaf(wreg[4 * c.value + 3][n.value], av.w, acc[n.value]);
            });
        });

        // partials: contiguous b128 store, conflict-free
        *reinterpret_cast<float4*>(&part[w][4 * lane]) =
            make_float4(acc[0], acc[1], acc[2], acc[3]);
        __syncthreads();

        // ---- reduce phase: waves 0-3 active, thread tid owns neuron tid
        if (tid < HID) {
            float s = b0_r;
            Unroll<NW>::run([&](auto ww) { s += part[ww.value][tid]; });
            float h = fast_tanh(s);
            a_buf[nxt][FEAT + tid] = h;
            if (tid < FEAT) a_buf[nxt][tid] = xnext;

            // out[b][t] = Wfc . h + bfc
            float p = wfc_r * h;
#pragma unroll
            for (int m = 32; m >= 1; m >>= 1) p += __shfl_xor(p, m, 64);
            if (lane == 0) {
                atomicAdd(&out[b * T_STEPS + t], p + (w == 0 ? bfc_r : 0.0f));
            }
        }
        __syncthreads();   // a_buf[nxt] complete before next step's FMA phase
    }
}

extern "C" void kernel_launch(void* const* d_in, const int* in_sizes, int n_in,
                              void* d_out, int out_size, void* d_ws, size_t ws_size,
                              hipStream_t stream) {
    const float* x   = (const float*)d_in[0];
    const float* W0  = (const float*)d_in[1];
    const float* b0  = (const float*)d_in[2];
    const float* Wfc = (const float*)d_in[3];
    const float* bfc = (const float*)d_in[4];
    // d_in[5] = feature_n == 0 -> no autoregressive tail
    float* out = (float*)d_out;

    hipMemsetAsync(out, 0, (size_t)out_size * sizeof(float), stream);
    rnn_kernel<<<dim3(BATCH), dim3(NTHR), 0, stream>>>(x, W0, b0, Wfc, bfc, out);
}

// Round 5
// 2139.918 us; speedup vs baseline: 1.1251x; 1.0433x over previous
//
#include <hip/hip_runtime.h>
#include <type_traits>
#include <utility>

// Problem constants: T=2048, B=256, F=64, H=256, O=1
#define T_STEPS 2048
#define BATCH   256
#define FEAT    64
#define HID     256
#define KAUG    320   // FEAT + HID
#define NTHR    1024  // threads per block = 16 waves = 4 waves/EU
#define NW      16    // waves per block
#define KCH     20    // KAUG / NW -> 80 weight VGPRs/lane

// R4 evidence: without an occupancy pin the backend budgeted 8 waves/EU
// (VGPR cap 64 -> granted 60) and spilled the 80 register-resident weights to
// scratch, reloading them from L2 every step (VALUBusy 42%). waves_per_eu(4,4)
// pins min=max=4 -> hard 128-VGPR budget; 80 weights + ~30 overhead fits.
// WRITE_SIZE=64MiB was the 2M global atomicAdds (32B write-through each), not
// spill -> replaced by LDS accumulation + one coalesced epilogue store.

template <int N>
struct Unroll {
    template <typename F>
    __device__ __forceinline__ static void run(F&& f) {
        Unroll<N - 1>::run(f);
        f(std::integral_constant<int, N - 1>{});
    }
};
template <>
struct Unroll<0> {
    template <typename F>
    __device__ __forceinline__ static void run(F&&) {}
};

// fast tanh: tanh(z) = 1 - 2/(exp(2z)+1). Saturates correctly at +/-inf.
__device__ __forceinline__ float fast_tanh(float z) {
    float e = __expf(2.0f * z);
    return 1.0f - 2.0f * __builtin_amdgcn_rcpf(e + 1.0f);
}

// One block per batch element (grid 256 = CU count, 1 block/CU).
// Wave w owns k-range [20w, 20w+20) of a=[x_t; h]; lane l owns neurons 4l..4l+3.
__global__
__attribute__((amdgpu_flat_work_group_size(NTHR, NTHR), amdgpu_waves_per_eu(4, 4)))
void rnn_kernel(const float* __restrict__ x,    // (T, B, F)
                const float* __restrict__ W0,   // (H, F+H) row-major
                const float* __restrict__ b0,   // (H)
                const float* __restrict__ Wfc,  // (1, H)
                const float* __restrict__ bfc,  // (1)
                float* __restrict__ out)        // (B, T)
{
    const int b    = blockIdx.x;
    const int tid  = threadIdx.x;
    const int w    = tid >> 6;
    const int lane = tid & 63;
    const int kbase = KCH * w;

    __shared__ float a_buf[2][KAUG];      // double-buffered augmented input (2.5 KB)
    __shared__ float part[NW][HID];       // per-wave partial sums (16 KB)
    __shared__ float out_buf[T_STEPS];    // per-step outputs (8 KB)

    // wreg[kk][n] = W0[4*lane+n][kbase+kk]  (80 VGPRs/lane), float4 global loads
    float wreg[KCH][4];
    Unroll<4>::run([&](auto n) {
        const float* w0p = W0 + (4 * lane + n.value) * KAUG + kbase;
        Unroll<KCH / 4>::run([&](auto c) {
            const float4 v = *reinterpret_cast<const float4*>(w0p + 4 * c.value);
            wreg[4 * c.value + 0][n.value] = v.x;
            wreg[4 * c.value + 1][n.value] = v.y;
            wreg[4 * c.value + 2][n.value] = v.z;
            wreg[4 * c.value + 3][n.value] = v.w;
        });
    });

    float b0_r = 0.0f, wfc_r = 0.0f;
    if (tid < HID) { b0_r = b0[tid]; wfc_r = Wfc[tid]; }
    const float bfc_r = bfc[0];

    // prologue: a_buf[0] = [x_0 ; h0=0]; out_buf[t] = bfc
    if (tid < FEAT) a_buf[0][tid] = x[b * FEAT + tid];
    if (tid < HID)  a_buf[0][FEAT + tid] = 0.0f;
    out_buf[tid]        = bfc_r;
    out_buf[tid + NTHR] = bfc_r;
    __syncthreads();

    for (int t = 0; t < T_STEPS; ++t) {
        const int cur = t & 1;
        const int nxt = cur ^ 1;

        // prefetch x for step t+1 (hidden under FMA phase)
        float xnext = 0.0f;
        if (tid < FEAT) {
            int tn = (t + 1 < T_STEPS) ? (t + 1) : t;
            xnext = x[tn * (BATCH * FEAT) + b * FEAT + tid];
        }

        // ---- FMA phase: 80 fp32 FMAs/lane, 4 independent acc chains,
        // fed by 5 uniform-address ds_read_b128 broadcasts (conflict-free)
        float acc[4] = {0.f, 0.f, 0.f, 0.f};
        const float4* a4 = reinterpret_cast<const float4*>(&a_buf[cur][kbase]);
        Unroll<KCH / 4>::run([&](auto c) {
            const float4 av = a4[c.value];
            Unroll<4>::run([&](auto n) {
                acc[n.value] = fmaf(wreg[4 * c.value + 0][n.value], av.x, acc[n.value]);
                acc[n.value] = fmaf(wreg[4 * c.value + 1][n.value], av.y, acc[n.value]);
                acc[n.value] = fmaf(wreg[4 * c.value + 2][n.value], av.z, acc[n.value]);
                acc[n.value] = fmaf(wreg[4 * c.value + 3][n.value], av.w, acc[n.value]);
            });
        });

        // partials: contiguous b128 store, conflict-free
        *reinterpret_cast<float4*>(&part[w][4 * lane]) =
            make_float4(acc[0], acc[1], acc[2], acc[3]);
        __syncthreads();

        // ---- reduce phase: waves 0-3, thread tid owns neuron tid
        if (tid < HID) {
            float s = b0_r;
            Unroll<NW>::run([&](auto ww) { s += part[ww.value][tid]; });
            float h = fast_tanh(s);
            a_buf[nxt][FEAT + tid] = h;
            if (tid < FEAT) a_buf[nxt][tid] = xnext;

            // out[b][t] = Wfc . h + bfc : wave-local shuffle reduce,
            // then one LDS ds_add_f32 per wave (no global atomics)
            float p = wfc_r * h;
#pragma unroll
            for (int m = 32; m >= 1; m >>= 1) p += __shfl_xor(p, m, 64);
            if (lane == 0) atomicAdd(&out_buf[t], p);
        }
        __syncthreads();   // a_buf[nxt] + out_buf[t] settled before reuse
    }

    // epilogue: coalesced float2 store of the block's 2048 outputs
    float2* o2 = reinterpret_cast<float2*>(out + b * T_STEPS);
    const float2* s2 = reinterpret_cast<const float2*>(out_buf);
    o2[tid] = s2[tid];
}

extern "C" void kernel_launch(void* const* d_in, const int* in_sizes, int n_in,
                              void* d_out, int out_size, void* d_ws, size_t ws_size,
                              hipStream_t stream) {
    const float* x   = (const float*)d_in[0];
    const float* W0  = (const float*)d_in[1];
    const float* b0  = (const float*)d_in[2];
    const float* Wfc = (const float*)d_in[3];
    const float* bfc = (const float*)d_in[4];
    // d_in[5] = feature_n == 0 -> no autoregressive tail
    float* out = (float*)d_out;

    rnn_kernel<<<dim3(BATCH), dim3(NTHR), 0, stream>>>(x, W0, b0, Wfc, bfc, out);
}

// Round 6
// 2117.844 us; speedup vs baseline: 1.1368x; 1.0104x over previous
//
#include <hip/hip_runtime.h>
#include <type_traits>
#include <utility>

// Problem constants: T=2048, B=256, F=64, H=256, O=1
#define T_STEPS 2048
#define BATCH   256
#define FEAT    64
#define HID     256
#define KAUG    320   // FEAT + H
#define NTHR    1024  // threads per block = 16 waves = 4 waves/EU
#define NW      16    // waves per block
#define KCH     20    // KAUG / NW -> 80 weight VGPRs/lane

// R5 evidence: no scratch writes (WRITE=2MB) yet VGPR_Count=60 -> the compiler
// REMATERIALIZES the weight loads every loop iteration (L2 re-reads), because
// its occupancy target stayed at 8 waves/EU (64-VGPR budget) despite
// waves_per_eu(4,4). Fix: pad LDS past 81920 B so only ONE 16-wave workgroup
// fits per CU -> max achievable occupancy is 4 waves/EU -> 128-VGPR budget.
// Grid is 256 blocks on 256 CUs (1 block/CU at runtime anyway) so the pad is
// free. 80 weights + ~30 working regs ~= 110 < 128 -> true register residency.

template <int N>
struct Unroll {
    template <typename F>
    __device__ __forceinline__ static void run(F&& f) {
        Unroll<N - 1>::run(f);
        f(std::integral_constant<int, N - 1>{});
    }
};
template <>
struct Unroll<0> {
    template <typename F>
    __device__ __forceinline__ static void run(F&&) {}
};

// fast tanh: tanh(z) = 1 - 2/(exp(2z)+1). Saturates correctly at +/-inf.
__device__ __forceinline__ float fast_tanh(float z) {
    float e = __expf(2.0f * z);
    return 1.0f - 2.0f * __builtin_amdgcn_rcpf(e + 1.0f);
}

// One block per batch element (grid 256 = CU count, 1 block/CU).
// Wave w owns k-range [20w, 20w+20) of a=[x_t; h]; lane l owns neurons 4l..4l+3.
__global__
__attribute__((amdgpu_flat_work_group_size(NTHR, NTHR), amdgpu_waves_per_eu(4, 4)))
void rnn_kernel(const float* __restrict__ x,    // (T, B, F)
                const float* __restrict__ W0,   // (H, F+H) row-major
                const float* __restrict__ b0,   // (H)
                const float* __restrict__ Wfc,  // (1, H)
                const float* __restrict__ bfc,  // (1)
                float* __restrict__ out)        // (B, T)
{
    const int b    = blockIdx.x;
    const int tid  = threadIdx.x;
    const int w    = tid >> 6;
    const int lane = tid & 63;
    const int kbase = KCH * w;

    __shared__ float a_buf[2][KAUG];      // double-buffered augmented input (2.5 KB)
    __shared__ float part[NW][HID];       // per-wave partial sums (16 KB)
    __shared__ float out_buf[T_STEPS];    // per-step outputs (8 KB)
    // Occupancy limiter: total LDS = 27136 + 56832 = 83968 B > 81920 B
    // -> only 1 workgroup/CU fits -> compiler budget = 128 VGPR/lane.
    __shared__ float lds_pad[14208];

    // keep lds_pad alive: blockIdx.x is runtime-unknown, branch never taken
    if (blockIdx.x == 0xFFFFFFFFu) {
        ((volatile float*)lds_pad)[tid] = 1.0f;
    }

    // wreg[kk][n] = W0[4*lane+n][kbase+kk]  (80 VGPRs/lane), float4 global loads
    float wreg[KCH][4];
    Unroll<4>::run([&](auto n) {
        const float* w0p = W0 + (4 * lane + n.value) * KAUG + kbase;
        Unroll<KCH / 4>::run([&](auto c) {
            const float4 v = *reinterpret_cast<const float4*>(w0p + 4 * c.value);
            wreg[4 * c.value + 0][n.value] = v.x;
            wreg[4 * c.value + 1][n.value] = v.y;
            wreg[4 * c.value + 2][n.value] = v.z;
            wreg[4 * c.value + 3][n.value] = v.w;
        });
    });

    float b0_r = 0.0f, wfc_r = 0.0f;
    if (tid < HID) { b0_r = b0[tid]; wfc_r = Wfc[tid]; }
    const float bfc_r = bfc[0];

    // prologue: a_buf[0] = [x_0 ; h0=0]; out_buf[t] = bfc
    if (tid < FEAT) a_buf[0][tid] = x[b * FEAT + tid];
    if (tid < HID)  a_buf[0][FEAT + tid] = 0.0f;
    out_buf[tid]        = bfc_r;
    out_buf[tid + NTHR] = bfc_r;
    __syncthreads();

    for (int t = 0; t < T_STEPS; ++t) {
        const int cur = t & 1;
        const int nxt = cur ^ 1;

        // prefetch x for step t+1 (hidden under FMA phase)
        float xnext = 0.0f;
        if (tid < FEAT) {
            int tn = (t + 1 < T_STEPS) ? (t + 1) : t;
            xnext = x[tn * (BATCH * FEAT) + b * FEAT + tid];
        }

        // ---- FMA phase: 80 fp32 FMAs/lane, 4 independent acc chains,
        // fed by 5 uniform-address ds_read_b128 broadcasts (conflict-free)
        float acc[4] = {0.f, 0.f, 0.f, 0.f};
        const float4* a4 = reinterpret_cast<const float4*>(&a_buf[cur][kbase]);
        Unroll<KCH / 4>::run([&](auto c) {
            const float4 av = a4[c.value];
            Unroll<4>::run([&](auto n) {
                acc[n.value] = fmaf(wreg[4 * c.value + 0][n.value], av.x, acc[n.value]);
                acc[n.value] = fmaf(wreg[4 * c.value + 1][n.value], av.y, acc[n.value]);
                acc[n.value] = fmaf(wreg[4 * c.value + 2][n.value], av.z, acc[n.value]);
                acc[n.value] = fmaf(wreg[4 * c.value + 3][n.value], av.w, acc[n.value]);
            });
        });

        // partials: contiguous b128 store, conflict-free
        *reinterpret_cast<float4*>(&part[w][4 * lane]) =
            make_float4(acc[0], acc[1], acc[2], acc[3]);
        __syncthreads();

        // ---- reduce phase: waves 0-3, thread tid owns neuron tid
        if (tid < HID) {
            float s = b0_r;
            Unroll<NW>::run([&](auto ww) { s += part[ww.value][tid]; });
            float h = fast_tanh(s);
            a_buf[nxt][FEAT + tid] = h;
            if (tid < FEAT) a_buf[nxt][tid] = xnext;

            // out[b][t] = Wfc . h + bfc : wave shuffle reduce + one LDS atomic
            float p = wfc_r * h;
#pragma unroll
            for (int m = 32; m >= 1; m >>= 1) p += __shfl_xor(p, m, 64);
            if (lane == 0) atomicAdd(&out_buf[t], p);
        }
        __syncthreads();   // a_buf[nxt] + out_buf[t] settled before reuse
    }

    // epilogue: coalesced float2 store of the block's 2048 outputs
    float2* o2 = reinterpret_cast<float2*>(out + b * T_STEPS);
    const float2* s2 = reinterpret_cast<const float2*>(out_buf);
    o2[tid] = s2[tid];
}

extern "C" void kernel_launch(void* const* d_in, const int* in_sizes, int n_in,
                              void* d_out, int out_size, void* d_ws, size_t ws_size,
                              hipStream_t stream) {
    const float* x   = (const float*)d_in[0];
    const float* W0  = (const float*)d_in[1];
    const float* b0  = (const float*)d_in[2];
    const float* Wfc = (const float*)d_in[3];
    const float* bfc = (const float*)d_in[4];
    // d_in[5] = feature_n == 0 -> no autoregressive tail
    float* out = (float*)d_out;

    rnn_kernel<<<dim3(BATCH), dim3(NTHR), 0, stream>>>(x, W0, b0, Wfc, bfc, out);
}